// Round 6
// baseline (116.355 us; speedup 1.0000x reference)
//
#include <hip/hip_runtime.h>
#include <hip/hip_fp16.h>
#include <math.h>

#define PATCH 41
#define PP 1681          // 41*41
#define NB 8
#define STRIDE 10
#define PAD 4
#define NTH 192          // 3 waves
#define XR 51            // f32 row stride (ODD: mixed-parity banks); phys col = j+6
#define HR 5             // s_H ox-slot stride (4 used + 1 pad)

__device__ __forceinline__ constexpr float tri16(int k) {
    float d = (float)k + 0.5f - 8.0f;
    float a = d < 0.0f ? -d : d;
    return (8.0f - a) * 0.125f;   // u[i]*u[j] == pk[i][j] bit-exactly; all values n*2^-4 (exact in f16)
}

// per-pixel core: grad + folded weight -> packed 8-bin f16 contrib (16B)
// (octant-direct binning + 64-bit-shift pack: validated R5-R9; UNCHANGED)
__device__ __forceinline__ uint4 pixel_contrib(float gx, float gy, float w) {
    float X = gx + 1e-10f;
    float mag = __builtin_amdgcn_sqrtf(fmaf(gx, gx, fmaf(gy, gy, 1e-10f))) * w;

    float ax = fabsf(X), ay = fabsf(gy);
    float mx = fmaxf(ax, ay), mn = fminf(ax, ay);
    float r = mn * __builtin_amdgcn_rcpf(fmaxf(mx, 1e-30f));
    float r2 = r * r;
    float a4 = fmaf(r2, -0.0149238f, 0.0670406f);
    a4 = fmaf(r2, a4, -0.1482457f);
    a4 = fmaf(r2, a4, 0.2464287f);
    a4 = fmaf(r2, a4, -0.4235106f);
    a4 = fmaf(r2, a4, 1.2732106f);
    a4 *= r;

    bool sw = ay > ax;
    bool xn = X < 0.0f;
    bool yn = gy < 0.0f;
    int q = (xn ? 2 : 0) + ((sw != xn) ? 1 : 0);
    int b0 = yn ? 7 - q : q;              // bin for (1-w1) mass
    bool f = (sw != xn) != yn;
    float ma = a4 * mag;
    float mb = mag - ma;
    float v0 = f ? ma : mb;               // mass for bin b0
    float v1 = f ? mb : ma;               // mass for bin (b0+1)&7

    unsigned combo = __builtin_bit_cast(unsigned, __builtin_amdgcn_cvt_pkrtz(v0, v1));
    int sh = (b0 & 3) << 4;
    unsigned long long A = (unsigned long long)combo << sh;
    unsigned long long B = ((b0 & 3) == 3) ? (unsigned long long)(combo >> 16) : 0ull;
    bool lohalf = b0 < 4;
    unsigned long long lo = lohalf ? A : B;
    unsigned long long hi = lohalf ? B : A;
    uint4 cw;
    cw.x = (unsigned)lo; cw.y = (unsigned)(lo >> 32);
    cw.z = (unsigned)hi; cw.w = (unsigned)(hi >> 32);
    return cw;
}

__device__ __forceinline__ __half2 u2h2(unsigned v) {
    return __builtin_bit_cast(__half2, v);
}

// lane i <- lane i-1 within its 16-lane DPP row; row-start lanes -> 0
// (old=0 means invalid lanes yield 0 under EITHER bound_ctrl interpretation)
__device__ __forceinline__ unsigned dpp_prev(unsigned v) {
    return (unsigned)__builtin_amdgcn_update_dpp(0, (int)v, 0x111, 0xF, 0xF, true); // row_shr:1
}
// lane i <- lane i+1 within its 16-lane DPP row; row-end lanes -> 0
__device__ __forceinline__ unsigned dpp_next(unsigned v) {
    return (unsigned)__builtin_amdgcn_update_dpp(0, (int)v, 0x101, 0xF, 0xF, true); // row_shl:1
}

// R6: batch-preload P1 inputs to registers. R5 showed VGPR stuck at 32 under
// launch_bounds(192,6): the compiler sinks ds_reads next to uses (11 serial
// lgkm stall points/thread, VALUBusy 62%). Named full-unroll arrays force
// the live ranges: all ~48 ds_read_b32 issue up front (merge to read2),
// ONE lgkmcnt wait, then pure VALU. Budget 85 VGPR @ 6 waves/EU covers the
// ~46-float working set.
__global__ __launch_bounds__(NTH, 6) void sift_desc_kernel(
        const float* __restrict__ x,   // [N,1,41,41]
        const float* __restrict__ gk,  // unused: recomputed via exp2
        const float* __restrict__ pk,  // unused: recomputed exactly
        float* __restrict__ out)       // [N,128]
{
    const int patch = blockIdx.x;
    const int t = threadIdx.x;

    __shared__ __align__(16) float s_xp[PATCH * XR];     // 8.4 KB f32 padded patch
    __shared__ __align__(16) float s_gc[48];             // column gauss (no tri, no OOB needed)
    __shared__ __align__(16) __half s_H[49 * HR * NB];   // 3.9 KB, rows 0-3,45+ zero
    __shared__ float s_desc[128];

    // ---- P0: stage patch (incremental i,j), gauss LUT, H-pad ----
    const float* xp = x + (size_t)patch * PP;
    {
        int i = t / PATCH;
        int j = t - i * PATCH;
        for (int p = t; p < PP; p += NTH) {
            s_xp[i * XR + j + 6] = xp[p];
            j += 28; i += 4;                       // 192 = 4*41 + 28
            if (j >= PATCH) { j -= PATCH; i += 1; }
        }
    }
    for (int q = t; q < 41 * 9; q += NTH) {        // pad cols j=-6..-1,41..43
        int i = q / 9;
        int c = q - i * 9;
        int j = (c < 6) ? (c - 6) : (c + 35);
        int jc = min(max(j, 0), PATCH - 1);
        s_xp[i * XR + j + 6] = xp[i * PATCH + jc];
    }
    if (t < 48) {                                   // column gaussian LUT (cols 0..40)
        float d = (float)(t - 20);
        float g = __builtin_amdgcn_exp2f(d * d * -8.582362e-4f);
        s_gc[t] = (t < PATCH) ? g : 0.0f;
    }
    if (t < 160) {                                  // zero H pad rows 0-3,45-48
        int dw = (t < 80) ? t : (820 + t);
        ((unsigned*)s_H)[dw] = 0u;
    }
    __syncthreads();

    // ---- P1+P2 fused, owned-pixel scheme + register preload ----
    // thread (row,ox) owns cols ox*10 .. ox*10+10 (its window kx=4..14): 11 evals.
    // Window slots kx=0..3 come from left lane (its k=6..9 ONLY — k=10 is col cb,
    // which we own ourselves; including it was the R1 bug), kx=15 from right
    // lane (its k=1) via DPP lane+-1. All 16-lane-row crossings coincide with
    // the ox0/ox3 edges which must be zero anyway (weight-mask / cndmask).
    if (t < PATCH * 4) {
        const int row = t >> 2;
        const int ox = t & 3;
        const int cb = ox * STRIDE;                            // own col base
        const int rowM = row * XR + cb + 6;                    // phys idx of col cb
        const int rowU = (row > 0 ? row - 1 : 0) * XR + cb + 6;
        const int rowD = (row < PATCH - 1 ? row + 1 : PATCH - 1) * XR + cb + 6;

        float drow = (float)(row - 20);
        const float rf = __builtin_amdgcn_exp2f(drow * drow * -8.582362e-4f);

        // Batched register preload: whole P1 working set, compile-time offsets.
        // m[i] = M-row col cb-1+i (i=0..12); gx(k) = m[k+2]-m[k].
        // u[i]/d[i] = up/down rows col cb+i (i=0..10); gy(k) = d[k]-u[k].
        float m[13], u[11], d[11], w[11];
        #pragma unroll
        for (int i = 0; i < 13; ++i) m[i] = s_xp[rowM - 1 + i];
        #pragma unroll
        for (int i = 0; i < 11; ++i) u[i] = s_xp[rowU + i];
        #pragma unroll
        for (int i = 0; i < 11; ++i) d[i] = s_xp[rowD + i];
        #pragma unroll
        for (int i = 0; i < 11; ++i) w[i] = s_gc[cb + i] * rf;

        const __half2 z2 = __float2half2_rn(0.0f);
        __half2 a0 = z2, a1 = z2, a2 = z2, a3 = z2;

        const bool ox0 = (ox == 0);
        const bool ox3 = (ox == 3);
        // left-recv weights tri16(0..3); zero for ox==0 (cols -4..-1)
        const __half2 wl[4] = {
            ox0 ? z2 : __float2half2_rn(tri16(0)),
            ox0 ? z2 : __float2half2_rn(tri16(1)),
            ox0 ? z2 : __float2half2_rn(tri16(2)),
            ox0 ? z2 : __float2half2_rn(tri16(3))
        };

        #pragma unroll
        for (int k = 0; k <= 10; ++k) {
            uint4 cw = pixel_contrib(m[k + 2] - m[k], d[k] - u[k], w[k]);

            // own window slot kx = k+4, exact-f16 tri constant
            const __half2 wo = __float2half2_rn(tri16(k + 4));
            a0 = __hfma2(u2h2(cw.x), wo, a0);
            a1 = __hfma2(u2h2(cw.y), wo, a1);
            a2 = __hfma2(u2h2(cw.z), wo, a2);
            a3 = __hfma2(u2h2(cw.w), wo, a3);

            if (k == 1) {
                // my kx=15 (col cb+11) = right lane's k=1 eval; tri16(15)
                unsigned rx = dpp_next(cw.x);
                unsigned ry = dpp_next(cw.y);
                unsigned rz = dpp_next(cw.z);
                unsigned rw = dpp_next(cw.w);
                // ox3: col 41 is OOB AND source may be another row / inactive
                // junk (t=163<-164) -> sanitize data, not just weight
                rx = ox3 ? 0u : rx;  ry = ox3 ? 0u : ry;
                rz = ox3 ? 0u : rz;  rw = ox3 ? 0u : rw;
                const __half2 wr = __float2half2_rn(tri16(15));
                a0 = __hfma2(u2h2(rx), wr, a0);
                a1 = __hfma2(u2h2(ry), wr, a1);
                a2 = __hfma2(u2h2(rz), wr, a2);
                a3 = __hfma2(u2h2(rw), wr, a3);
            }
            if (k >= 6 && k < 10) {
                // my kx = k-6 (cols cb-4..cb-1) = left lane's k=6..9 evals ONLY;
                // (left lane's k=10 is col cb = my own k=0 — must NOT be added.
                // The unguarded k=10 case was the R1 bug: duplicate + wl[4] UB.)
                // ox0 weight is 0 (left source is prev row's ox3 - real finite
                // data, killed by the zero weight; row-start lanes DPP-zero)
                const __half2 wk = wl[k - 6];
                a0 = __hfma2(u2h2(dpp_prev(cw.x)), wk, a0);
                a1 = __hfma2(u2h2(dpp_prev(cw.y)), wk, a1);
                a2 = __hfma2(u2h2(dpp_prev(cw.z)), wk, a2);
                a3 = __hfma2(u2h2(dpp_prev(cw.w)), wk, a3);
            }
        }

        uint4 hv;
        hv.x = __builtin_bit_cast(unsigned, a0);
        hv.y = __builtin_bit_cast(unsigned, a1);
        hv.z = __builtin_bit_cast(unsigned, a2);
        hv.w = __builtin_bit_cast(unsigned, a3);
        *(uint4*)&s_H[((row + 4) * HR + ox) * NB] = hv;   // phys row = row+4
    }
    __syncthreads();

    // ---- P3: vertical pool over zero-padded H: no clamps, pure fma ----
    if (t < 128) {
        int b = t >> 4;
        int oy = (t >> 2) & 3;
        int ox = t & 3;
        const __half* hp = &s_H[(oy * STRIDE * HR + ox) * NB + b]; // phys row oy*10
        float v = 0.0f;
        #pragma unroll
        for (int ky = 0; ky < 16; ++ky) {
            v = fmaf(tri16(ky), __half2float(hp[ky * HR * NB]), v);
        }
        s_desc[t] = v;
    }
    __syncthreads();

    // ---- P4: single-wave normalization chain + store ----
    if (t < 64) {
        float a = s_desc[t];
        float b = s_desc[t + 64];

        float ss = fmaf(a, a, b * b);
        #pragma unroll
        for (int o = 32; o > 0; o >>= 1) ss += __shfl_xor(ss, o);
        float inv = 1.0f / fmaxf(__builtin_amdgcn_sqrtf(ss), 1e-12f);
        a = fminf(fmaxf(a * inv, 0.0f), 0.2f);
        b = fminf(fmaxf(b * inv, 0.0f), 0.2f);

        float ss2 = fmaf(a, a, b * b);
        #pragma unroll
        for (int o = 32; o > 0; o >>= 1) ss2 += __shfl_xor(ss2, o);
        float inv2 = 1.0f / fmaxf(__builtin_amdgcn_sqrtf(ss2), 1e-12f);
        a *= inv2; b *= inv2;

        float l1 = a + b;                      // a,b >= 0 after clip
        #pragma unroll
        for (int o = 32; o > 0; o >>= 1) l1 += __shfl_xor(l1, o);
        float invl = 1.0f / fmaxf(l1, 1e-12f);

        float* op = out + (size_t)patch * 128;
        op[t]      = __builtin_amdgcn_sqrtf(fmaf(a, invl, 1e-10f));
        op[t + 64] = __builtin_amdgcn_sqrtf(fmaf(b, invl, 1e-10f));
    }
}

extern "C" void kernel_launch(void* const* d_in, const int* in_sizes, int n_in,
                              void* d_out, int out_size, void* d_ws, size_t ws_size,
                              hipStream_t stream) {
    const float* x  = (const float*)d_in[0];
    const float* gk = (const float*)d_in[1];
    const float* pk = (const float*)d_in[2];
    float* out = (float*)d_out;
    const int n = in_sizes[0] / PP;   // 8192 patches
    sift_desc_kernel<<<n, NTH, 0, stream>>>(x, gk, pk, out);
}

// Round 7
// 108.859 us; speedup vs baseline: 1.0689x; 1.0689x over previous
//
#include <hip/hip_runtime.h>
#include <hip/hip_fp16.h>
#include <math.h>

#define PATCH 41
#define PP 1681          // 41*41
#define NB 8
#define STRIDE 10
#define NTH 192          // 3 waves
#define HR 5             // s_H ox-slot stride (4 used + 1 pad)
#define PPB 4            // patches per block (persistent, prefetch-pipelined)
#define TAIL (PP - 8 * NTH)   // 145

__device__ __forceinline__ constexpr float tri16(int k) {
    float d = (float)k + 0.5f - 8.0f;
    float a = d < 0.0f ? -d : d;
    return (8.0f - a) * 0.125f;   // u[i]*u[j] == pk[i][j] bit-exactly; all values n*2^-4 (exact in f16)
}

// per-pixel core: grad + folded weight -> packed 8-bin f16 contrib (16B)
// (octant-direct binning + 64-bit-shift pack: validated; UNCHANGED)
__device__ __forceinline__ uint4 pixel_contrib(float gx, float gy, float w) {
    float X = gx + 1e-10f;
    float mag = __builtin_amdgcn_sqrtf(fmaf(gx, gx, fmaf(gy, gy, 1e-10f))) * w;

    float ax = fabsf(X), ay = fabsf(gy);
    float mx = fmaxf(ax, ay), mn = fminf(ax, ay);
    float r = mn * __builtin_amdgcn_rcpf(fmaxf(mx, 1e-30f));
    float r2 = r * r;
    float a4 = fmaf(r2, -0.0149238f, 0.0670406f);
    a4 = fmaf(r2, a4, -0.1482457f);
    a4 = fmaf(r2, a4, 0.2464287f);
    a4 = fmaf(r2, a4, -0.4235106f);
    a4 = fmaf(r2, a4, 1.2732106f);
    a4 *= r;

    bool sw = ay > ax;
    bool xn = X < 0.0f;
    bool yn = gy < 0.0f;
    int q = (xn ? 2 : 0) + ((sw != xn) ? 1 : 0);
    int b0 = yn ? 7 - q : q;              // bin for (1-w1) mass
    bool f = (sw != xn) != yn;
    float ma = a4 * mag;
    float mb = mag - ma;
    float v0 = f ? ma : mb;               // mass for bin b0
    float v1 = f ? mb : ma;               // mass for bin (b0+1)&7

    unsigned combo = __builtin_bit_cast(unsigned, __builtin_amdgcn_cvt_pkrtz(v0, v1));
    int sh = (b0 & 3) << 4;
    unsigned long long A = (unsigned long long)combo << sh;
    unsigned long long B = ((b0 & 3) == 3) ? (unsigned long long)(combo >> 16) : 0ull;
    bool lohalf = b0 < 4;
    unsigned long long lo = lohalf ? A : B;
    unsigned long long hi = lohalf ? B : A;
    uint4 cw;
    cw.x = (unsigned)lo; cw.y = (unsigned)(lo >> 32);
    cw.z = (unsigned)hi; cw.w = (unsigned)(hi >> 32);
    return cw;
}

__device__ __forceinline__ __half2 u2h2(unsigned v) {
    return __builtin_bit_cast(__half2, v);
}

// lane i <- lane i-1 within its 16-lane DPP row; row-start lanes -> 0
__device__ __forceinline__ unsigned dpp_prev(unsigned v) {
    return (unsigned)__builtin_amdgcn_update_dpp(0, (int)v, 0x111, 0xF, 0xF, true); // row_shr:1
}
// lane i <- lane i+1 within its 16-lane DPP row; row-end lanes -> 0
__device__ __forceinline__ unsigned dpp_next(unsigned v) {
    return (unsigned)__builtin_amdgcn_update_dpp(0, (int)v, 0x101, 0xF, 0xF, true); // row_shl:1
}

// R7: persistent blocks, PPB=4 patches each, double-buffered raw-41 LDS.
// R5/R6 falsified intra-P1 latency theory (VGPR pinned 32, dur flat) -> the
// ~38% idle is CORRELATED stall: per-patch P0 global-load drain at the first
// barrier + phase tails. Fix: while P1 computes patch i, the 9 staging loads
// for patch i+1 are in flight (issue-early, ds_write-late = T14); drain is
// hidden under ~1400cy of VALU. sched_barrier(0) pins the loads above P1
// (the R5/R6 sink pathology). Raw stride-41 layout (2-way banks = free)
// kills the pad loop + div-by-9; m[0]/m[12] index-clamp reproduces the
// replicate-pad values bit-exactly.
__global__ __launch_bounds__(NTH, 6) void sift_desc_kernel(
        const float* __restrict__ x,   // [N,1,41,41]
        const float* __restrict__ gk,  // unused: recomputed via exp2
        const float* __restrict__ pk,  // unused: recomputed exactly
        float* __restrict__ out,       // [N,128]
        int n)
{
    const int t = threadIdx.x;
    const int base = blockIdx.x * PPB;

    __shared__ __align__(16) float sA[PP];               // 6.7 KB raw patch buf A
    __shared__ __align__(16) float sB[PP];               // 6.7 KB raw patch buf B
    __shared__ __align__(16) float s_gc[48];             // column gauss
    __shared__ __align__(16) __half s_H[49 * HR * NB];   // 3.9 KB, rows 0-3,45+ zero
    __shared__ float s_desc[128];

    // ---- one-time LUTs ----
    if (t < 48) {
        float dd = (float)(t - 20);
        float g = __builtin_amdgcn_exp2f(dd * dd * -8.582362e-4f);
        s_gc[t] = (t < PATCH) ? g : 0.0f;
    }
    if (t < 160) {                                  // zero H pad rows 0-3,45-48
        int dw = (t < 80) ? t : (820 + t);
        ((unsigned*)s_H)[dw] = 0u;
    }

    // ---- per-thread P1 constants (valid for t<164; harmless garbage else) ----
    const int row = t >> 2;
    const int ox  = t & 3;
    const int cb  = ox * STRIDE;
    const bool ox0 = (ox == 0);
    const bool ox3 = (ox == 3);
    const float drow = (float)(row - 20);
    const float rf = __builtin_amdgcn_exp2f(drow * drow * -8.582362e-4f);
    const __half2 z2 = __float2half2_rn(0.0f);
    const __half2 wl[4] = {
        ox0 ? z2 : __float2half2_rn(tri16(0)),
        ox0 ? z2 : __float2half2_rn(tri16(1)),
        ox0 ? z2 : __float2half2_rn(tri16(2)),
        ox0 ? z2 : __float2half2_rn(tri16(3))
    };
    const int rb = row * PATCH + cb;                                      // M row base (col cb)
    const int ru = (row > 0 ? row - 1 : 0) * PATCH + cb;                  // up row
    const int rd = (row < PATCH - 1 ? row + 1 : PATCH - 1) * PATCH + cb;  // down row

    // ---- stage patch base+0 into sA (batched: all loads, then all writes) ----
    {
        const float* gp = x + (size_t)base * PP;
        float stg[9];
        #pragma unroll
        for (int it = 0; it < 8; ++it) stg[it] = gp[it * NTH + t];
        stg[8] = (t < TAIL) ? gp[8 * NTH + t] : 0.0f;
        #pragma unroll
        for (int it = 0; it < 8; ++it) sA[it * NTH + t] = stg[it];
        if (t < TAIL) sA[8 * NTH + t] = stg[8];
    }
    __syncthreads();

    #pragma unroll
    for (int pi = 0; pi < PPB; ++pi) {
        if (base + pi >= n) break;                       // uniform guard
        const float* sC = (pi & 1) ? sB : sA;            // folds to concrete array
        float*       sN = (pi & 1) ? sA : sB;
        const bool hn = (pi + 1 < PPB) && (base + pi + 1 < n);

        // -- issue next-patch staging loads EARLY (drain hides under P1) --
        float stg[9];
        if (hn) {
            const float* gp = x + (size_t)(base + pi + 1) * PP;
            #pragma unroll
            for (int it = 0; it < 8; ++it) stg[it] = gp[it * NTH + t];
            stg[8] = (t < TAIL) ? gp[8 * NTH + t] : 0.0f;
        }
        __builtin_amdgcn_sched_barrier(0);   // pin: loads stay above P1 (R5/R6 sink fix)

        // ---- P1+P2 fused, owned-pixel scheme (validated R2) ----
        if (t < PATCH * 4) {
            float m[13], u[11], d[11], w[11];
            // m: cols cb-1 .. cb+11, ends index-clamped == replicate pad
            m[0]  = sC[rb + (ox0 ? 0 : -1)];
            #pragma unroll
            for (int i = 1; i < 12; ++i) m[i] = sC[rb + i - 1];
            m[12] = sC[rb + (ox3 ? 10 : 11)];
            #pragma unroll
            for (int i = 0; i < 11; ++i) u[i] = sC[ru + i];
            #pragma unroll
            for (int i = 0; i < 11; ++i) d[i] = sC[rd + i];
            #pragma unroll
            for (int i = 0; i < 11; ++i) w[i] = s_gc[cb + i] * rf;

            __half2 a0 = z2, a1 = z2, a2 = z2, a3 = z2;

            #pragma unroll
            for (int k = 0; k <= 10; ++k) {
                uint4 cw = pixel_contrib(m[k + 2] - m[k], d[k] - u[k], w[k]);

                // own window slot kx = k+4, exact-f16 tri constant
                const __half2 wo = __float2half2_rn(tri16(k + 4));
                a0 = __hfma2(u2h2(cw.x), wo, a0);
                a1 = __hfma2(u2h2(cw.y), wo, a1);
                a2 = __hfma2(u2h2(cw.z), wo, a2);
                a3 = __hfma2(u2h2(cw.w), wo, a3);

                if (k == 1) {
                    // my kx=15 (col cb+11) = right lane's k=1 eval; tri16(15)
                    unsigned rx = dpp_next(cw.x);
                    unsigned ry = dpp_next(cw.y);
                    unsigned rz = dpp_next(cw.z);
                    unsigned rw = dpp_next(cw.w);
                    rx = ox3 ? 0u : rx;  ry = ox3 ? 0u : ry;   // ox3: OOB + junk-src
                    rz = ox3 ? 0u : rz;  rw = ox3 ? 0u : rw;
                    const __half2 wr = __float2half2_rn(tri16(15));
                    a0 = __hfma2(u2h2(rx), wr, a0);
                    a1 = __hfma2(u2h2(ry), wr, a1);
                    a2 = __hfma2(u2h2(rz), wr, a2);
                    a3 = __hfma2(u2h2(rw), wr, a3);
                }
                if (k >= 6 && k < 10) {
                    // kx = k-6 = left lane's k=6..9 ONLY (k=10 dup was R1 bug);
                    // ox0 weight zero kills prev-row data; row-start DPP-zero
                    const __half2 wk = wl[k - 6];
                    a0 = __hfma2(u2h2(dpp_prev(cw.x)), wk, a0);
                    a1 = __hfma2(u2h2(dpp_prev(cw.y)), wk, a1);
                    a2 = __hfma2(u2h2(dpp_prev(cw.z)), wk, a2);
                    a3 = __hfma2(u2h2(dpp_prev(cw.w)), wk, a3);
                }
            }

            uint4 hv;
            hv.x = __builtin_bit_cast(unsigned, a0);
            hv.y = __builtin_bit_cast(unsigned, a1);
            hv.z = __builtin_bit_cast(unsigned, a2);
            hv.w = __builtin_bit_cast(unsigned, a3);
            *(uint4*)&s_H[((row + 4) * HR + ox) * NB] = hv;   // phys row = row+4
        }

        // -- write staged data LATE (vmcnt wait lands here, after P1 compute) --
        if (hn) {
            #pragma unroll
            for (int it = 0; it < 8; ++it) sN[it * NTH + t] = stg[it];
            if (t < TAIL) sN[8 * NTH + t] = stg[8];
        }
        __syncthreads();

        // ---- P3: vertical pool over zero-padded H ----
        if (t < 128) {
            int b  = t >> 4;
            int oy = (t >> 2) & 3;
            int oxx = t & 3;
            const __half* hp = &s_H[(oy * STRIDE * HR + oxx) * NB + b];
            float v = 0.0f;
            #pragma unroll
            for (int ky = 0; ky < 16; ++ky) {
                v = fmaf(tri16(ky), __half2float(hp[ky * HR * NB]), v);
            }
            s_desc[t] = v;
        }
        __syncthreads();

        // ---- P4: single-wave normalization chain + store ----
        if (t < 64) {
            float a = s_desc[t];
            float b = s_desc[t + 64];

            float ss = fmaf(a, a, b * b);
            #pragma unroll
            for (int o = 32; o > 0; o >>= 1) ss += __shfl_xor(ss, o);
            float inv = 1.0f / fmaxf(__builtin_amdgcn_sqrtf(ss), 1e-12f);
            a = fminf(fmaxf(a * inv, 0.0f), 0.2f);
            b = fminf(fmaxf(b * inv, 0.0f), 0.2f);

            float ss2 = fmaf(a, a, b * b);
            #pragma unroll
            for (int o = 32; o > 0; o >>= 1) ss2 += __shfl_xor(ss2, o);
            float inv2 = 1.0f / fmaxf(__builtin_amdgcn_sqrtf(ss2), 1e-12f);
            a *= inv2; b *= inv2;

            float l1 = a + b;
            #pragma unroll
            for (int o = 32; o > 0; o >>= 1) l1 += __shfl_xor(l1, o);
            float invl = 1.0f / fmaxf(l1, 1e-12f);

            float* op = out + (size_t)(base + pi) * 128;
            op[t]      = __builtin_amdgcn_sqrtf(fmaf(a, invl, 1e-10f));
            op[t + 64] = __builtin_amdgcn_sqrtf(fmaf(b, invl, 1e-10f));
        }
        // no extra barrier: next P1 reads sN (ready pre-barrier-1); next staging
        // writes sC only after this iter's post-P3 barrier. Race-free.
    }
}

extern "C" void kernel_launch(void* const* d_in, const int* in_sizes, int n_in,
                              void* d_out, int out_size, void* d_ws, size_t ws_size,
                              hipStream_t stream) {
    const float* x  = (const float*)d_in[0];
    const float* gk = (const float*)d_in[1];
    const float* pk = (const float*)d_in[2];
    float* out = (float*)d_out;
    const int n = in_sizes[0] / PP;   // 8192 patches
    const int grid = (n + PPB - 1) / PPB;
    sift_desc_kernel<<<grid, NTH, 0, stream>>>(x, gk, pk, out, n);
}